// Round 15
// baseline (87.710 us; speedup 1.0000x reference)
//
#include <hip/hip_runtime.h>
#include <hip/hip_bf16.h>
#include <stdint.h>

#define LSEQ 2048
#define NBATCH 2
#define NHEADS 16
#define HDIM 64
#define EMB 1024

typedef __bf16 bf16x8 __attribute__((ext_vector_type(8)));
typedef float f32x4 __attribute__((ext_vector_type(4)));
typedef unsigned short ushort4v __attribute__((ext_vector_type(4)));
typedef unsigned short ushort8v __attribute__((ext_vector_type(8)));

// Q is prescaled by c = log2e/32 so QK^T MFMA yields log2-domain logits
// directly; the fixed-max bias 2^(-96c) cancels in acc/ssum (p <= ~4).
#define QSCALE (1.44269504088896f / 32.0f)

static __device__ __forceinline__ unsigned short f2bf(float f) {
  union { float f; uint32_t u; } v; v.f = f;
  uint32_t u = v.u;
  u += 0x7fffu + ((u >> 16) & 1u);   // RNE
  return (unsigned short)(u >> 16);
}

static __device__ __forceinline__ f32x4 mfma16(bf16x8 a, bf16x8 b, f32x4 c) {
  return __builtin_amdgcn_mfma_f32_16x16x32_bf16(a, b, c, 0, 0, 0);
}

// masked exp2: bit b of m selects exp2(e) or 0.0 (2 VALU: sbfe + and)
static __device__ __forceinline__ float mexp2(float e, uint32_t m, int b) {
  uint32_t keep = (uint32_t)__builtin_amdgcn_sbfe((int)m, b, 1);
  return __uint_as_float(__float_as_uint(__builtin_amdgcn_exp2f(e)) & keep);
}

// ---- prep: Q(scaled),K(swizzled) convert, Wo convert, mask->bytes, VT ----
// blocks [0,8192): QK. [8192,9216): Wo. [9216,13312): mask. [13312,15360): VT.
__global__ __launch_bounds__(256) void prep_kernel(
    const float* __restrict__ q, const float* __restrict__ k,
    const float* __restrict__ w, const int* __restrict__ mask,
    const float* __restrict__ v,
    unsigned short* __restrict__ qb, unsigned short* __restrict__ kb,
    unsigned short* __restrict__ wb, unsigned char* __restrict__ mb8,
    unsigned short* __restrict__ vt) {
  int b = blockIdx.x;
  if (b < 8192) {
    int idx = b * 256 + threadIdx.x;          // 2 * 2^20 float4 granules
    const float* src; unsigned short* dst; int t; int swz;
    if (idx < (1 << 20)) { src = q; dst = qb; t = idx; swz = 0; }
    else                 { src = k; dst = kb; t = idx - (1 << 20); swz = 1; }
    int e = t << 2;
    int d = e & 63;
    int h = (e >> 6) & 15;
    int l = (e >> 10) & (LSEQ - 1);
    int n = e >> 21;
    float4 vv = reinterpret_cast<const float4*>(src)[t];
    int dd = d;
    if (swz) dd = ((((d >> 3) ^ (l & 7)) << 3) | (d & 7));
    else { vv.x *= QSCALE; vv.y *= QSCALE; vv.z *= QSCALE; vv.w *= QSCALE; }
    ushort4v o;
    o.x = f2bf(vv.x); o.y = f2bf(vv.y); o.z = f2bf(vv.z); o.w = f2bf(vv.w);
    size_t oi = (((size_t)n * NHEADS + h) * LSEQ + l) * HDIM + dd;
    *reinterpret_cast<ushort4v*>(dst + oi) = o;
  } else if (b < 9216) {
    int t = (b - 8192) * 256 + threadIdx.x;   // 2^18 float4 granules
    float4 vv = reinterpret_cast<const float4*>(w)[t];
    ushort4v o;
    o.x = f2bf(vv.x); o.y = f2bf(vv.y); o.z = f2bf(vv.z); o.w = f2bf(vv.w);
    reinterpret_cast<ushort4v*>(wb)[t] = o;
  } else if (b < 13312) {
    int idx = (b - 9216) * 256 + threadIdx.x; // 1M threads, 8 ints each
    const int* mp = mask + (size_t)idx * 8;
    int4 m0 = *reinterpret_cast<const int4*>(mp);
    int4 m1 = *reinterpret_cast<const int4*>(mp + 4);
    unsigned int bb = (m0.x ? 1u : 0u) | (m0.y ? 2u : 0u) | (m0.z ? 4u : 0u) |
                      (m0.w ? 8u : 0u) | (m1.x ? 16u : 0u) | (m1.y ? 32u : 0u) |
                      (m1.z ? 64u : 0u) | (m1.w ? 128u : 0u);
    mb8[idx] = (unsigned char)bb;
  } else {
    // V -> VT chunks [n][h][kc][d][slot32]; slot order = PV B-frag order:
    // slot s (g=s>>3, j=s&7): kp = (j<4) ? 4g+j : 16+4g+(j-4)
    // 16B-granule bank swizzle: c' = c ^ ((d>>1)&3)   (measured 0 conflicts)
    int b2 = b - 13312;              // n*16*64 + h*64 + kc
    int kc = b2 & 63;
    int h  = (b2 >> 6) & 15;
    int n  = b2 >> 10;
    int t  = threadIdx.x;
    int d    = t & 63;
    int sgrp = t >> 6;
    const float* src = v + (size_t)n * LSEQ * EMB + h * HDIM + d;
    ushort8v o;
#pragma unroll
    for (int j = 0; j < 8; ++j) {
      int kp = (j < 4) ? (4 * sgrp + j) : (16 + 4 * sgrp + (j - 4));
      float f = src[(size_t)(kc * 32 + kp) * EMB];
      o[j] = f2bf(f);
    }
    int cs = sgrp ^ ((d >> 1) & 3);
    size_t base = (((size_t)(n * NHEADS + h) * 64 + kc) * HDIM + d) * 32 + (cs << 3);
    *reinterpret_cast<ushort8v*>(vt + base) = o;
  }
}

// ---- Flash attention: 256-thr block (4 waves), K+V LDS dbuf KVBLK=64, ----
// 16 q-rows/wave, 32 KB LDS -> 5 blocks/CU = 20 waves/CU, MFMA-ssum.
__global__ __launch_bounds__(256, 5) void attn_kernel(
    const unsigned short* __restrict__ Kb, const unsigned short* __restrict__ Qb,
    const unsigned short* __restrict__ VT, const uint32_t* __restrict__ maskw,
    unsigned short* __restrict__ Op) {
  __shared__ unsigned short lds[2][8192];  // [buf][K:0..4095 | V:4096..8191]

  int bid = blockIdx.x;
  bid = (bid & 7) * 128 + (bid >> 3);  // XCD swizzle (1024 blocks, bijective)
  int qt = bid & 31;
  int h  = (bid >> 5) & 15;
  int n  = bid >> 9;
  int tid  = threadIdx.x;
  int wave = tid >> 6;
  int lane = tid & 63;
  int g  = lane >> 4;
  int qi = lane & 15;
  int qrow = qt * 64 + wave * 16 + qi;

  const unsigned short* qptr = Qb + (((size_t)n * NHEADS + h) * LSEQ + qrow) * HDIM;
  bf16x8 bq0 = *reinterpret_cast<const bf16x8*>(qptr + g * 8);        // d 0..31
  bf16x8 bq1 = *reinterpret_cast<const bf16x8*>(qptr + 32 + g * 8);   // d 32..63

  const unsigned short* khead  = Kb + (((size_t)n * NHEADS + h) * LSEQ) * HDIM;
  const unsigned short* vthead = VT + ((size_t)(n * NHEADS + h) * 64) * (HDIM * 32);
  const uint32_t* mrow = maskw + ((size_t)n * LSEQ + qrow) * 64;

  // Loop-invariant LDS fragment offsets (shorts), swizzled
  int xk = qi & 7;
  int kA = qi * 64 + ((g ^ xk) << 3);
  int kB = qi * 64 + (((4 + g) ^ xk) << 3);
  int kC = kA + 1024;
  int kD = kB + 1024;
  int xv = (qi >> 1) & 3;
  int vA = qi * 32 + ((g ^ xv) << 3);

  // all-ones A fragment: sacc = ones(16x32) @ P accumulates the full
  // per-q-column sum across all k (replaces VALU ssum + shfl reduce).
  union { uint32_t u[4]; bf16x8 v; } ones;
  ones.u[0] = 0x3F803F80u; ones.u[1] = 0x3F803F80u;
  ones.u[2] = 0x3F803F80u; ones.u[3] = 0x3F803F80u;

  f32x4 z = {0.f, 0.f, 0.f, 0.f};
  f32x4 acc0 = z, acc1 = z, acc2 = z, acc3 = z;   // out^T[d][q]
  f32x4 sacc = z;                                  // softmax denominator

#define STAGE(T, BUF) do {                                                     \
    const unsigned short* kg_ = khead  + (size_t)(T) * 4096 + tid * 8;         \
    const unsigned short* vg_ = vthead + (size_t)(T) * 4096 + tid * 8;         \
    _Pragma("unroll")                                                          \
    for (int j_ = 0; j_ < 2; ++j_) {                                           \
      __builtin_amdgcn_global_load_lds(                                        \
          (const __attribute__((address_space(1))) uint32_t*)(kg_ + j_ * 2048),\
          (__attribute__((address_space(3))) uint32_t*)                        \
              &lds[BUF][j_ * 2048 + wave * 512],                               \
          16, 0, 0);                                                           \
      __builtin_amdgcn_global_load_lds(                                        \
          (const __attribute__((address_space(1))) uint32_t*)(vg_ + j_ * 2048),\
          (__attribute__((address_space(3))) uint32_t*)                        \
              &lds[BUF][4096 + j_ * 2048 + wave * 512],                        \
          16, 0, 0);                                                           \
    }                                                                          \
  } while (0)

#define COMPUTE(BUF, CH, MW) do {                                              \
    const unsigned short* lk_ = &lds[BUF][(CH) * 2048];                        \
    const unsigned short* lv_ = &lds[BUF][4096 + (CH) * 2048];                 \
    bf16x8 K0 = *(const bf16x8*)(lk_ + kA);                                    \
    bf16x8 K1 = *(const bf16x8*)(lk_ + kB);                                    \
    bf16x8 K2 = *(const bf16x8*)(lk_ + kC);                                    \
    bf16x8 K3 = *(const bf16x8*)(lk_ + kD);                                    \
    f32x4 e0 = z, e1 = z;                                                      \
    e0 = mfma16(K0, bq0, e0); e0 = mfma16(K1, bq1, e0);                        \
    e1 = mfma16(K2, bq0, e1); e1 = mfma16(K3, bq1, e1);                        \
    bf16x8 V0 = *(const bf16x8*)(lv_ + vA);                                    \
    bf16x8 V1 = *(const bf16x8*)(lv_ + vA + 512);                              \
    bf16x8 V2 = *(const bf16x8*)(lv_ + vA + 1024);                             \
    bf16x8 V3 = *(const bf16x8*)(lv_ + vA + 1536);                             \
    uint32_t m0_ = (MW) >> (4 * g);                                            \
    uint32_t m1_ = (MW) >> (16 + 4 * g);                                       \
    float p0 = mexp2(e0[0], m0_, 0);                                           \
    float p1 = mexp2(e0[1], m0_, 1);                                           \
    float p2 = mexp2(e0[2], m0_, 2);                                           \
    float p3 = mexp2(e0[3], m0_, 3);                                           \
    float p4 = mexp2(e1[0], m1_, 0);                                           \
    float p5 = mexp2(e1[1], m1_, 1);                                           \
    float p6 = mexp2(e1[2], m1_, 2);                                           \
    float p7 = mexp2(e1[3], m1_, 3);                                           \
    union { uint32_t u[4]; bf16x8 v; } pf;                                     \
    asm("v_cvt_pk_bf16_f32 %0, %1, %2" : "=v"(pf.u[0]) : "v"(p0), "v"(p1));    \
    asm("v_cvt_pk_bf16_f32 %0, %1, %2" : "=v"(pf.u[1]) : "v"(p2), "v"(p3));    \
    asm("v_cvt_pk_bf16_f32 %0, %1, %2" : "=v"(pf.u[2]) : "v"(p4), "v"(p5));    \
    asm("v_cvt_pk_bf16_f32 %0, %1, %2" : "=v"(pf.u[3]) : "v"(p6), "v"(p7));    \
    acc0 = mfma16(V0, pf.v, acc0);                                             \
    acc1 = mfma16(V1, pf.v, acc1);                                             \
    acc2 = mfma16(V2, pf.v, acc2);                                             \
    acc3 = mfma16(V3, pf.v, acc3);                                             \
    sacc = mfma16(ones.v, pf.v, sacc);                                         \
  } while (0)

  uint64_t mw0 = *(const uint64_t*)(mrow);
  uint64_t mw1, mw2;
  STAGE(0, 0);
  __syncthreads();

  for (int t = 0; t < 32; t += 2) {
    int t1 = (t + 1) & 31;
    mw1 = *(const uint64_t*)(mrow + 2 * t1);
    STAGE(t1, 1);
    COMPUTE(0, 0, (uint32_t)mw0);
    COMPUTE(0, 1, (uint32_t)(mw0 >> 32));
    __syncthreads();
    int t2 = (t + 2) & 31;
    mw2 = *(const uint64_t*)(mrow + 2 * t2);
    STAGE(t2, 0);
    COMPUTE(1, 0, (uint32_t)mw1);
    COMPUTE(1, 1, (uint32_t)(mw1 >> 32));
    __syncthreads();
    mw0 = mw2;
  }
#undef STAGE
#undef COMPUTE

  float inv = 1.0f / sacc[0];

  size_t ob = ((size_t)n * LSEQ + qrow) * EMB + h * HDIM;
  ushort4v s0, s1, s2, s3;
#pragma unroll
  for (int r = 0; r < 4; ++r) {
    s0[r] = f2bf(acc0[r] * inv);
    s1[r] = f2bf(acc1[r] * inv);
    s2[r] = f2bf(acc2[r] * inv);
    s3[r] = f2bf(acc3[r] * inv);
  }
  *reinterpret_cast<ushort4v*>(Op + ob + 0  + 4 * g) = s0;
  *reinterpret_cast<ushort4v*>(Op + ob + 16 + 4 * g) = s1;
  *reinterpret_cast<ushort4v*>(Op + ob + 32 + 4 * g) = s2;
  *reinterpret_cast<ushort4v*>(Op + ob + 48 + 4 * g) = s3;
}

// ---- Projection: 128x64 tile, LDS dbuf with 2 k-panels per phase ----------
__global__ __launch_bounds__(256, 2) void proj_kernel(
    const unsigned short* __restrict__ A, const unsigned short* __restrict__ B,
    const float* __restrict__ bo, float* __restrict__ out) {
  __shared__ unsigned short plds[2][12288];  // [buf][panel0: A|B, panel1: A|B]

  int bid = blockIdx.x;
  bid = (bid & 7) * 64 + (bid >> 3);  // XCD swizzle (512 blocks)
  int mb0 = (bid >> 4) * 128;
  int nb0 = (bid & 15) * 64;
  int tid  = threadIdx.x;
  int wave = tid >> 6;
  int lane = tid & 63;
  int g  = lane >> 4;
  int qi = lane & 15;
  int wm = wave >> 1, wn = wave & 1;

  // staging source (inverse-swizzled global read -> linear LDS dest)
  int srow = tid >> 2;
  int scol = (((tid & 3) ^ ((tid >> 3) & 3)) << 3);
  const unsigned short* aS0 = A + (size_t)(mb0 + srow) * EMB + scol;
  const unsigned short* aS1 = aS0 + (size_t)64 * EMB;
  const unsigned short* bS  = B + (size_t)(nb0 + srow) * EMB + scol;

  // swizzled ds_read offsets (shorts)
  int xa = (qi >> 1) & 3;
  int gof = ((g ^ xa) << 3);
  int aof0 = (wm * 64 + qi) * 32 + gof;
  int aof1 = aof0 + 16 * 32;
  int aof2 = aof0 + 32 * 32;
  int aof3 = aof0 + 48 * 32;
  int bof0 = (wn * 32 + qi) * 32 + gof;
  int bof1 = bof0 + 16 * 32;

  f32x4 z = {0.f, 0.f, 0.f, 0.f};
  f32x4 acc00 = z, acc01 = z, acc10 = z, acc11 = z;
  f32x4 acc20 = z, acc21 = z, acc30 = z, acc31 = z;

#define PSTAGE2(KT, BUF) do {                                                  \
    _Pragma("unroll")                                                          \
    for (int p_ = 0; p_ < 2; ++p_) {                                           \
      int kt_ = ((KT) + p_) & 31;                                              \
      __builtin_amdgcn_global_load_lds(                                        \
          (const __attribute__((address_space(1))) uint32_t*)(aS0 + kt_ * 32), \
          (__attribute__((address_space(3))) uint32_t*)                        \
              &plds[BUF][p_ * 6144 + wave * 512],                              \
          16, 0, 0);                                                           \
      __builtin_amdgcn_global_load_lds(                                        \
          (const __attribute__((address_space(1))) uint32_t*)(aS1 + kt_ * 32), \
          (__attribute__((address_space(3))) uint32_t*)                        \
              &plds[BUF][p_ * 6144 + 2048 + wave * 512],                       \
          16, 0, 0);                                                           \
      __builtin_amdgcn_global_load_lds(                                        \
          (const __attribute__((address_space(1))) uint32_t*)(bS + kt_ * 32),  \
          (__attribute__((address_space(3))) uint32_t*)                        \
              &plds[BUF][p_ * 6144 + 4096 + wave * 512],                       \
          16, 0, 0);                                                           \
    }                                                                          \
  } while (0)

#define PCOMPUTE(BUF, P) do {                                                  \
    const unsigned short* la_ = &plds[BUF][(P) * 6144];                        \
    const unsigned short* lb_ = &plds[BUF][(P) * 6144 + 4096];                 \
    bf16x8 a0 = *(const bf16x8*)(la_ + aof0);                                  \
    bf16x8 a1 = *(const bf16x8*)(la_ + aof1);                                  \
    bf16x8 a2 = *(const bf16x8*)(la_ + aof2);                                  \
    bf16x8 a3 = *(const bf16x8*)(la_ + aof3);                                  \
    bf16x8 b0 = *(const bf16x8*)(lb_ + bof0);                                  \
    bf16x8 b1 = *(const bf16x8*)(lb_ + bof1);                                  \
    acc00 = mfma16(a0, b0, acc00); acc01 = mfma16(a0, b1, acc01);              \
    acc10 = mfma16(a1, b0, acc10); acc11 = mfma16(a1, b1, acc11);              \
    acc20 = mfma16(a2, b0, acc20); acc21 = mfma16(a2, b1, acc21);              \
    acc30 = mfma16(a3, b0, acc30); acc31 = mfma16(a3, b1, acc31);              \
  } while (0)

  PSTAGE2(0, 0);
  __syncthreads();
  for (int kt = 0; kt < 32; kt += 4) {
    PSTAGE2(kt + 2, 1);
    PCOMPUTE(0, 0);
    PCOMPUTE(0, 1);
    __syncthreads();
    PSTAGE2((kt + 4) & 31, 0);
    PCOMPUTE(1, 0);
    PCOMPUTE(1, 1);
    __syncthreads();
  }
#undef PSTAGE2
#undef PCOMPUTE

  int orow = mb0 + wm * 64 + 4 * g;
  int col0 = nb0 + wn * 32 + qi;
  float bia0 = bo[col0];
  float bia1 = bo[col0 + 16];
#define PSTORE(ACC0, ACC1, M) do {                                             \
    _Pragma("unroll")                                                          \
    for (int r = 0; r < 4; ++r) {                                              \
      size_t rw = (size_t)(orow + (M) * 16 + r) * EMB;                         \
      out[rw + col0]      = ACC0[r] + bia0;                                    \
      out[rw + col0 + 16] = ACC1[r] + bia1;                                    \
    }                                                                          \
  } while (0)
  PSTORE(acc00, acc01, 0);
  PSTORE(acc10, acc11, 1);
  PSTORE(acc20, acc21, 2);
  PSTORE(acc30, acc31, 3);
#undef PSTORE
}

extern "C" void kernel_launch(void* const* d_in, const int* in_sizes, int n_in,
                              void* d_out, int out_size, void* d_ws, size_t ws_size,
                              hipStream_t stream) {
  const float* Vf   = (const float*)d_in[0];
  const float* Kf   = (const float*)d_in[1];
  const float* Qf   = (const float*)d_in[2];
  const int*   Mask = (const int*)d_in[3];
  const float* Wo   = (const float*)d_in[4];
  const float* Bo   = (const float*)d_in[5];
  float* out = (float*)d_out;

  char* ws = (char*)d_ws;
  // ws layout (bytes): Qb 8MB | Kb 8MB | VT 8MB | Wob 2MB | Opb 8MB | Mb 1MB
  unsigned short* Qb  = (unsigned short*)(ws);
  unsigned short* Kb  = (unsigned short*)(ws + (size_t)8  * 1024 * 1024);
  unsigned short* VTb = (unsigned short*)(ws + (size_t)16 * 1024 * 1024);
  unsigned short* Wob = (unsigned short*)(ws + (size_t)24 * 1024 * 1024);
  unsigned short* Opb = (unsigned short*)(ws + (size_t)26 * 1024 * 1024);
  unsigned char*  Mb  = (unsigned char*)(ws + (size_t)34 * 1024 * 1024);

  prep_kernel<<<15360, 256, 0, stream>>>(Qf, Kf, Wo, Mask, Vf, Qb, Kb, Wob, Mb, VTb);
  attn_kernel<<<1024, 256, 0, stream>>>(Kb, Qb, VTb, (const uint32_t*)Mb, Opb);
  proj_kernel<<<512, 256, 0, stream>>>(Opb, Wob, Bo, out);
}

// Round 16
// 82.570 us; speedup vs baseline: 1.0623x; 1.0623x over previous
//
#include <hip/hip_runtime.h>
#include <hip/hip_bf16.h>
#include <stdint.h>

#define LSEQ 2048
#define NBATCH 2
#define NHEADS 16
#define HDIM 64
#define EMB 1024

typedef __bf16 bf16x8 __attribute__((ext_vector_type(8)));
typedef float f32x4 __attribute__((ext_vector_type(4)));
typedef unsigned short ushort4v __attribute__((ext_vector_type(4)));
typedef unsigned short ushort8v __attribute__((ext_vector_type(8)));

// Q is prescaled by c = log2e/32 so QK^T MFMA yields log2-domain logits
// directly; the fixed-max bias 2^(-96c) cancels in acc/ssum (p <= ~4).
#define QSCALE (1.44269504088896f / 32.0f)

static __device__ __forceinline__ unsigned short f2bf(float f) {
  union { float f; uint32_t u; } v; v.f = f;
  uint32_t u = v.u;
  u += 0x7fffu + ((u >> 16) & 1u);   // RNE
  return (unsigned short)(u >> 16);
}

static __device__ __forceinline__ f32x4 mfma16(bf16x8 a, bf16x8 b, f32x4 c) {
  return __builtin_amdgcn_mfma_f32_16x16x32_bf16(a, b, c, 0, 0, 0);
}

// masked exp2: bit b of m selects exp2(e) or 0.0 (2 VALU: sbfe + and)
static __device__ __forceinline__ float mexp2(float e, uint32_t m, int b) {
  uint32_t keep = (uint32_t)__builtin_amdgcn_sbfe((int)m, b, 1);
  return __uint_as_float(__float_as_uint(__builtin_amdgcn_exp2f(e)) & keep);
}

// ---- prep: Q(scaled),K(swizzled) convert, Wo convert, mask->bytes, VT ----
// blocks [0,8192): QK. [8192,9216): Wo. [9216,13312): mask. [13312,15360): VT.
__global__ __launch_bounds__(256) void prep_kernel(
    const float* __restrict__ q, const float* __restrict__ k,
    const float* __restrict__ w, const int* __restrict__ mask,
    const float* __restrict__ v,
    unsigned short* __restrict__ qb, unsigned short* __restrict__ kb,
    unsigned short* __restrict__ wb, unsigned char* __restrict__ mb8,
    unsigned short* __restrict__ vt) {
  int b = blockIdx.x;
  if (b < 8192) {
    int idx = b * 256 + threadIdx.x;          // 2 * 2^20 float4 granules
    const float* src; unsigned short* dst; int t; int swz;
    if (idx < (1 << 20)) { src = q; dst = qb; t = idx; swz = 0; }
    else                 { src = k; dst = kb; t = idx - (1 << 20); swz = 1; }
    int e = t << 2;
    int d = e & 63;
    int h = (e >> 6) & 15;
    int l = (e >> 10) & (LSEQ - 1);
    int n = e >> 21;
    float4 vv = reinterpret_cast<const float4*>(src)[t];
    int dd = d;
    if (swz) dd = ((((d >> 3) ^ (l & 7)) << 3) | (d & 7));
    else { vv.x *= QSCALE; vv.y *= QSCALE; vv.z *= QSCALE; vv.w *= QSCALE; }
    ushort4v o;
    o.x = f2bf(vv.x); o.y = f2bf(vv.y); o.z = f2bf(vv.z); o.w = f2bf(vv.w);
    size_t oi = (((size_t)n * NHEADS + h) * LSEQ + l) * HDIM + dd;
    *reinterpret_cast<ushort4v*>(dst + oi) = o;
  } else if (b < 9216) {
    int t = (b - 8192) * 256 + threadIdx.x;   // 2^18 float4 granules
    float4 vv = reinterpret_cast<const float4*>(w)[t];
    ushort4v o;
    o.x = f2bf(vv.x); o.y = f2bf(vv.y); o.z = f2bf(vv.z); o.w = f2bf(vv.w);
    reinterpret_cast<ushort4v*>(wb)[t] = o;
  } else if (b < 13312) {
    int idx = (b - 9216) * 256 + threadIdx.x; // 1M threads, 8 ints each
    const int* mp = mask + (size_t)idx * 8;
    int4 m0 = *reinterpret_cast<const int4*>(mp);
    int4 m1 = *reinterpret_cast<const int4*>(mp + 4);
    unsigned int bb = (m0.x ? 1u : 0u) | (m0.y ? 2u : 0u) | (m0.z ? 4u : 0u) |
                      (m0.w ? 8u : 0u) | (m1.x ? 16u : 0u) | (m1.y ? 32u : 0u) |
                      (m1.z ? 64u : 0u) | (m1.w ? 128u : 0u);
    mb8[idx] = (unsigned char)bb;
  } else {
    // V -> VT chunks [n][h][kc][d][slot32]; slot order = PV B-frag order:
    // slot s (g=s>>3, j=s&7): kp = (j<4) ? 4g+j : 16+4g+(j-4)
    // 16B-granule bank swizzle: c' = c ^ ((d>>1)&3)   (measured 0 conflicts)
    int b2 = b - 13312;              // n*16*64 + h*64 + kc
    int kc = b2 & 63;
    int h  = (b2 >> 6) & 15;
    int n  = b2 >> 10;
    int t  = threadIdx.x;
    int d    = t & 63;
    int sgrp = t >> 6;
    const float* src = v + (size_t)n * LSEQ * EMB + h * HDIM + d;
    ushort8v o;
#pragma unroll
    for (int j = 0; j < 8; ++j) {
      int kp = (j < 4) ? (4 * sgrp + j) : (16 + 4 * sgrp + (j - 4));
      float f = src[(size_t)(kc * 32 + kp) * EMB];
      o[j] = f2bf(f);
    }
    int cs = sgrp ^ ((d >> 1) & 3);
    size_t base = (((size_t)(n * NHEADS + h) * 64 + kc) * HDIM + d) * 32 + (cs << 3);
    *reinterpret_cast<ushort8v*>(vt + base) = o;
  }
}

// ---- Flash attention: 512-thr block (8 waves), K+V LDS dbuf KVBLK=128, ----
// 16 q-rows/wave, 2 blocks/CU -> 4 waves/SIMD, MFMA-ssum. (round-14 best)
__global__ __launch_bounds__(512, 4) void attn_kernel(
    const unsigned short* __restrict__ Kb, const unsigned short* __restrict__ Qb,
    const unsigned short* __restrict__ VT, const uint32_t* __restrict__ maskw,
    unsigned short* __restrict__ Op) {
  __shared__ unsigned short lds[2][16384];  // [buf][K:0..8191 | V:8192..16383]

  int bid = blockIdx.x;
  bid = (bid & 7) * 64 + (bid >> 3);  // XCD swizzle (512 blocks, bijective)
  int qt = bid & 15;
  int h  = (bid >> 4) & 15;
  int n  = bid >> 8;
  int tid  = threadIdx.x;
  int wave = tid >> 6;
  int lane = tid & 63;
  int g  = lane >> 4;
  int qi = lane & 15;
  int qrow = qt * 128 + wave * 16 + qi;

  const unsigned short* qptr = Qb + (((size_t)n * NHEADS + h) * LSEQ + qrow) * HDIM;
  bf16x8 bq0 = *reinterpret_cast<const bf16x8*>(qptr + g * 8);        // d 0..31
  bf16x8 bq1 = *reinterpret_cast<const bf16x8*>(qptr + 32 + g * 8);   // d 32..63

  const unsigned short* khead  = Kb + (((size_t)n * NHEADS + h) * LSEQ) * HDIM;
  const unsigned short* vthead = VT + ((size_t)(n * NHEADS + h) * 64) * (HDIM * 32);
  const uint32_t* mrow = maskw + ((size_t)n * LSEQ + qrow) * 64;

  // Loop-invariant LDS fragment offsets (shorts), swizzled
  int xk = qi & 7;
  int kA = qi * 64 + ((g ^ xk) << 3);
  int kB = qi * 64 + (((4 + g) ^ xk) << 3);
  int kC = kA + 1024;
  int kD = kB + 1024;
  int xv = (qi >> 1) & 3;
  int vA = qi * 32 + ((g ^ xv) << 3);

  // all-ones A fragment: sacc = ones(16x32) @ P accumulates the full
  // per-q-column sum across all k (replaces VALU ssum + shfl reduce).
  union { uint32_t u[4]; bf16x8 v; } ones;
  ones.u[0] = 0x3F803F80u; ones.u[1] = 0x3F803F80u;
  ones.u[2] = 0x3F803F80u; ones.u[3] = 0x3F803F80u;

  f32x4 z = {0.f, 0.f, 0.f, 0.f};
  f32x4 acc0 = z, acc1 = z, acc2 = z, acc3 = z;   // out^T[d][q]
  f32x4 sacc = z;                                  // softmax denominator

#define STAGE(T, BUF) do {                                                     \
    const unsigned short* kg_ = khead  + (size_t)(T) * 8192 + tid * 8;         \
    const unsigned short* vg_ = vthead + (size_t)(T) * 8192 + tid * 8;         \
    _Pragma("unroll")                                                          \
    for (int j_ = 0; j_ < 2; ++j_) {                                           \
      __builtin_amdgcn_global_load_lds(                                        \
          (const __attribute__((address_space(1))) uint32_t*)(kg_ + j_ * 4096),\
          (__attribute__((address_space(3))) uint32_t*)                        \
              &lds[BUF][j_ * 4096 + wave * 512],                               \
          16, 0, 0);                                                           \
      __builtin_amdgcn_global_load_lds(                                        \
          (const __attribute__((address_space(1))) uint32_t*)(vg_ + j_ * 4096),\
          (__attribute__((address_space(3))) uint32_t*)                        \
              &lds[BUF][8192 + j_ * 4096 + wave * 512],                        \
          16, 0, 0);                                                           \
    }                                                                          \
  } while (0)

#define COMPUTE(BUF, CH, MW) do {                                              \
    const unsigned short* lk_ = &lds[BUF][(CH) * 2048];                        \
    const unsigned short* lv_ = &lds[BUF][8192 + (CH) * 2048];                 \
    bf16x8 K0 = *(const bf16x8*)(lk_ + kA);                                    \
    bf16x8 K1 = *(const bf16x8*)(lk_ + kB);                                    \
    bf16x8 K2 = *(const bf16x8*)(lk_ + kC);                                    \
    bf16x8 K3 = *(const bf16x8*)(lk_ + kD);                                    \
    f32x4 e0 = z, e1 = z;                                                      \
    e0 = mfma16(K0, bq0, e0); e0 = mfma16(K1, bq1, e0);                        \
    e1 = mfma16(K2, bq0, e1); e1 = mfma16(K3, bq1, e1);                        \
    bf16x8 V0 = *(const bf16x8*)(lv_ + vA);                                    \
    bf16x8 V1 = *(const bf16x8*)(lv_ + vA + 512);                              \
    bf16x8 V2 = *(const bf16x8*)(lv_ + vA + 1024);                             \
    bf16x8 V3 = *(const bf16x8*)(lv_ + vA + 1536);                             \
    uint32_t m0_ = (MW) >> (4 * g);                                            \
    uint32_t m1_ = (MW) >> (16 + 4 * g);                                       \
    float p0 = mexp2(e0[0], m0_, 0);                                           \
    float p1 = mexp2(e0[1], m0_, 1);                                           \
    float p2 = mexp2(e0[2], m0_, 2);                                           \
    float p3 = mexp2(e0[3], m0_, 3);                                           \
    float p4 = mexp2(e1[0], m1_, 0);                                           \
    float p5 = mexp2(e1[1], m1_, 1);                                           \
    float p6 = mexp2(e1[2], m1_, 2);                                           \
    float p7 = mexp2(e1[3], m1_, 3);                                           \
    union { uint32_t u[4]; bf16x8 v; } pf;                                     \
    asm("v_cvt_pk_bf16_f32 %0, %1, %2" : "=v"(pf.u[0]) : "v"(p0), "v"(p1));    \
    asm("v_cvt_pk_bf16_f32 %0, %1, %2" : "=v"(pf.u[1]) : "v"(p2), "v"(p3));    \
    asm("v_cvt_pk_bf16_f32 %0, %1, %2" : "=v"(pf.u[2]) : "v"(p4), "v"(p5));    \
    asm("v_cvt_pk_bf16_f32 %0, %1, %2" : "=v"(pf.u[3]) : "v"(p6), "v"(p7));    \
    acc0 = mfma16(V0, pf.v, acc0);                                             \
    acc1 = mfma16(V1, pf.v, acc1);                                             \
    acc2 = mfma16(V2, pf.v, acc2);                                             \
    acc3 = mfma16(V3, pf.v, acc3);                                             \
    sacc = mfma16(ones.v, pf.v, sacc);                                         \
  } while (0)

  uint4 mw0 = *(const uint4*)(mrow);
  uint4 mw1, mw2;
  STAGE(0, 0);
  __syncthreads();

  for (int t = 0; t < 16; t += 2) {
    int t1 = (t + 1) & 15;
    mw1 = *(const uint4*)(mrow + 4 * t1);
    STAGE(t1, 1);
    COMPUTE(0, 0, mw0.x);
    COMPUTE(0, 1, mw0.y);
    COMPUTE(0, 2, mw0.z);
    COMPUTE(0, 3, mw0.w);
    __syncthreads();
    int t2 = (t + 2) & 15;
    mw2 = *(const uint4*)(mrow + 4 * t2);
    STAGE(t2, 0);
    COMPUTE(1, 0, mw1.x);
    COMPUTE(1, 1, mw1.y);
    COMPUTE(1, 2, mw1.z);
    COMPUTE(1, 3, mw1.w);
    __syncthreads();
    mw0 = mw2;
  }
#undef STAGE
#undef COMPUTE

  float inv = 1.0f / sacc[0];

  size_t ob = ((size_t)n * LSEQ + qrow) * EMB + h * HDIM;
  ushort4v s0, s1, s2, s3;
#pragma unroll
  for (int r = 0; r < 4; ++r) {
    s0[r] = f2bf(acc0[r] * inv);
    s1[r] = f2bf(acc1[r] * inv);
    s2[r] = f2bf(acc2[r] * inv);
    s3[r] = f2bf(acc3[r] * inv);
  }
  *reinterpret_cast<ushort4v*>(Op + ob + 0  + 4 * g) = s0;
  *reinterpret_cast<ushort4v*>(Op + ob + 16 + 4 * g) = s1;
  *reinterpret_cast<ushort4v*>(Op + ob + 32 + 4 * g) = s2;
  *reinterpret_cast<ushort4v*>(Op + ob + 48 + 4 * g) = s3;
}

// ---- Projection: 128x64 tile, LDS dbuf with 2 k-panels per phase ----------
__global__ __launch_bounds__(256, 2) void proj_kernel(
    const unsigned short* __restrict__ A, const unsigned short* __restrict__ B,
    const float* __restrict__ bo, float* __restrict__ out) {
  __shared__ unsigned short plds[2][12288];  // [buf][panel0: A|B, panel1: A|B]

  int bid = blockIdx.x;
  bid = (bid & 7) * 64 + (bid >> 3);  // XCD swizzle (512 blocks)
  int mb0 = (bid >> 4) * 128;
  int nb0 = (bid & 15) * 64;
  int tid  = threadIdx.x;
  int wave = tid >> 6;
  int lane = tid & 63;
  int g  = lane >> 4;
  int qi = lane & 15;
  int wm = wave >> 1, wn = wave & 1;

  // staging source (inverse-swizzled global read -> linear LDS dest)
  int srow = tid >> 2;
  int scol = (((tid & 3) ^ ((tid >> 3) & 3)) << 3);
  const unsigned short* aS0 = A + (size_t)(mb0 + srow) * EMB + scol;
  const unsigned short* aS1 = aS0 + (size_t)64 * EMB;
  const unsigned short* bS  = B + (size_t)(nb0 + srow) * EMB + scol;

  // swizzled ds_read offsets (shorts)
  int xa = (qi >> 1) & 3;
  int gof = ((g ^ xa) << 3);
  int aof0 = (wm * 64 + qi) * 32 + gof;
  int aof1 = aof0 + 16 * 32;
  int aof2 = aof0 + 32 * 32;
  int aof3 = aof0 + 48 * 32;
  int bof0 = (wn * 32 + qi) * 32 + gof;
  int bof1 = bof0 + 16 * 32;

  f32x4 z = {0.f, 0.f, 0.f, 0.f};
  f32x4 acc00 = z, acc01 = z, acc10 = z, acc11 = z;
  f32x4 acc20 = z, acc21 = z, acc30 = z, acc31 = z;

#define PSTAGE2(KT, BUF) do {                                                  \
    _Pragma("unroll")                                                          \
    for (int p_ = 0; p_ < 2; ++p_) {                                           \
      int kt_ = ((KT) + p_) & 31;                                              \
      __builtin_amdgcn_global_load_lds(                                        \
          (const __attribute__((address_space(1))) uint32_t*)(aS0 + kt_ * 32), \
          (__attribute__((address_space(3))) uint32_t*)                        \
              &plds[BUF][p_ * 6144 + wave * 512],                              \
          16, 0, 0);                                                           \
      __builtin_amdgcn_global_load_lds(                                        \
          (const __attribute__((address_space(1))) uint32_t*)(aS1 + kt_ * 32), \
          (__attribute__((address_space(3))) uint32_t*)                        \
              &plds[BUF][p_ * 6144 + 2048 + wave * 512],                       \
          16, 0, 0);                                                           \
      __builtin_amdgcn_global_load_lds(                                        \
          (const __attribute__((address_space(1))) uint32_t*)(bS + kt_ * 32),  \
          (__attribute__((address_space(3))) uint32_t*)                        \
              &plds[BUF][p_ * 6144 + 4096 + wave * 512],                       \
          16, 0, 0);                                                           \
    }                                                                          \
  } while (0)

#define PCOMPUTE(BUF, P) do {                                                  \
    const unsigned short* la_ = &plds[BUF][(P) * 6144];                        \
    const unsigned short* lb_ = &plds[BUF][(P) * 6144 + 4096];                 \
    bf16x8 a0 = *(const bf16x8*)(la_ + aof0);                                  \
    bf16x8 a1 = *(const bf16x8*)(la_ + aof1);                                  \
    bf16x8 a2 = *(const bf16x8*)(la_ + aof2);                                  \
    bf16x8 a3 = *(const bf16x8*)(la_ + aof3);                                  \
    bf16x8 b0 = *(const bf16x8*)(lb_ + bof0);                                  \
    bf16x8 b1 = *(const bf16x8*)(lb_ + bof1);                                  \
    acc00 = mfma16(a0, b0, acc00); acc01 = mfma16(a0, b1, acc01);              \
    acc10 = mfma16(a1, b0, acc10); acc11 = mfma16(a1, b1, acc11);              \
    acc20 = mfma16(a2, b0, acc20); acc21 = mfma16(a2, b1, acc21);              \
    acc30 = mfma16(a3, b0, acc30); acc31 = mfma16(a3, b1, acc31);              \
  } while (0)

  PSTAGE2(0, 0);
  __syncthreads();
  for (int kt = 0; kt < 32; kt += 4) {
    PSTAGE2(kt + 2, 1);
    PCOMPUTE(0, 0);
    PCOMPUTE(0, 1);
    __syncthreads();
    PSTAGE2((kt + 4) & 31, 0);
    PCOMPUTE(1, 0);
    PCOMPUTE(1, 1);
    __syncthreads();
  }
#undef PSTAGE2
#undef PCOMPUTE

  int orow = mb0 + wm * 64 + 4 * g;
  int col0 = nb0 + wn * 32 + qi;
  float bia0 = bo[col0];
  float bia1 = bo[col0 + 16];
#define PSTORE(ACC0, ACC1, M) do {                                             \
    _Pragma("unroll")                                                          \
    for (int r = 0; r < 4; ++r) {                                              \
      size_t rw = (size_t)(orow + (M) * 16 + r) * EMB;                         \
      out[rw + col0]      = ACC0[r] + bia0;                                    \
      out[rw + col0 + 16] = ACC1[r] + bia1;                                    \
    }                                                                          \
  } while (0)
  PSTORE(acc00, acc01, 0);
  PSTORE(acc10, acc11, 1);
  PSTORE(acc20, acc21, 2);
  PSTORE(acc30, acc31, 3);
#undef PSTORE
}

extern "C" void kernel_launch(void* const* d_in, const int* in_sizes, int n_in,
                              void* d_out, int out_size, void* d_ws, size_t ws_size,
                              hipStream_t stream) {
  const float* Vf   = (const float*)d_in[0];
  const float* Kf   = (const float*)d_in[1];
  const float* Qf   = (const float*)d_in[2];
  const int*   Mask = (const int*)d_in[3];
  const float* Wo   = (const float*)d_in[4];
  const float* Bo   = (const float*)d_in[5];
  float* out = (float*)d_out;

  char* ws = (char*)d_ws;
  // ws layout (bytes): Qb 8MB | Kb 8MB | VT 8MB | Wob 2MB | Opb 8MB | Mb 1MB
  unsigned short* Qb  = (unsigned short*)(ws);
  unsigned short* Kb  = (unsigned short*)(ws + (size_t)8  * 1024 * 1024);
  unsigned short* VTb = (unsigned short*)(ws + (size_t)16 * 1024 * 1024);
  unsigned short* Wob = (unsigned short*)(ws + (size_t)24 * 1024 * 1024);
  unsigned short* Opb = (unsigned short*)(ws + (size_t)26 * 1024 * 1024);
  unsigned char*  Mb  = (unsigned char*)(ws + (size_t)34 * 1024 * 1024);

  prep_kernel<<<15360, 256, 0, stream>>>(Qf, Kf, Wo, Mask, Vf, Qb, Kb, Wob, Mb, VTb);
  attn_kernel<<<512, 512, 0, stream>>>(Kb, Qb, VTb, (const uint32_t*)Mb, Opb);
  proj_kernel<<<512, 256, 0, stream>>>(Opb, Wob, Bo, out);
}